// Round 5
// baseline (443.958 us; speedup 1.0000x reference)
//
#include <hip/hip_runtime.h>

typedef short short8 __attribute__((ext_vector_type(8)));
typedef float f32x4 __attribute__((ext_vector_type(4)));
typedef float f32x16 __attribute__((ext_vector_type(16)));
typedef float v2f __attribute__((ext_vector_type(2)));
typedef unsigned int uint32;
typedef uint32 u32x4 __attribute__((ext_vector_type(4)));

namespace {
constexpr int S_LEN = 512, BATCH = 1024, TAG = 64;
constexpr int START_IDX = 0, END_IDX = 1;
constexpr int PD = 4;  // renorm cadence == prefetch depth

__device__ __forceinline__ uint32 pack_bf16_trunc(float lo, float hi) {
  return __builtin_amdgcn_perm(__float_as_uint(hi), __float_as_uint(lo), 0x07060302u);
}
}  // namespace

// ---------------- kernel 1: per-(batch,chunk) transfer matrix, 32x32x16 MFMA ----------------
// M <- diag(exp(feat_s)) * (E * M), E = exp(trans) in A-frags (32 VGPRs).
// LDS (per buffer, 8 KiB): element (k,n) at byte
//   (( k>>4)*2 + (n>>5))*1024 + ((n&31) + 32*((k>>3)&1))*16 + (k&7)*2
// -> B-frag read (kt,nc): byte (kt*2+nc)*1024 + lane*16   (lane-contiguous b128)
// -> D-write (mr,nc,gr):  b64 at ((2mr+(gr>>1))*2+nc)*1024 + (c31+32*(gr&1))*16 + 8h
// Double-buffered: step s reads buf[s&1], writes buf[(s+1)&1] (no WAR pinning needed).
__global__ __launch_bounds__(64, 3) void crf_chunk_kernel(
    const float* __restrict__ feats, const float* __restrict__ mask,
    const float* __restrict__ trans, uint32* __restrict__ wsM,
    float* __restrict__ wsL, int K, int L, int kshift) {
  const int bc = blockIdx.x;
  const int b = bc >> kshift;
  const int c = bc & (K - 1);
  const int lane = threadIdx.x;
  const int c31 = lane & 31, h = lane >> 5;

  __shared__ __align__(16) unsigned short Mlds[2][TAG * TAG];
  __shared__ __align__(16) float f_lds[TAG];

  // ---- init buf0 = I ----
  {
    u32x4 z = {0u, 0u, 0u, 0u};
    u32x4* p = (u32x4*)&Mlds[0][0];
#pragma unroll
    for (int t = 0; t < 8; ++t) p[lane + 64 * t] = z;
    __builtin_amdgcn_wave_barrier();
    const int i = lane;  // (k=i, n=i) <- bf16 1.0
    char* idp = (char*)&Mlds[0][0] + ((i >> 4) * 2 + (i >> 5)) * 1024 +
                ((i & 31) + 32 * ((i >> 3) & 1)) * 16 + (i & 7) * 2;
    *(unsigned short*)idp = 0x3F80;
    __builtin_amdgcn_wave_barrier();
  }

  // ---- E A-frags: tile (mr,kt): A[m=32mr+c31][k=16kt+8h+j] ----
  short8 Ef[2][4];
#pragma unroll
  for (int mr = 0; mr < 2; ++mr)
#pragma unroll
    for (int kt = 0; kt < 4; ++kt) {
      const float* src = trans + (32 * mr + c31) * TAG + 16 * kt + 8 * h;
      f32x4 t0, t1;
      __builtin_memcpy(&t0, src, 16);
      __builtin_memcpy(&t1, src + 4, 16);
      uint32 uu[4];
      uu[0] = pack_bf16_trunc(__expf(t0.x), __expf(t0.y));  // exp(-1e4) -> 0, no NaN
      uu[1] = pack_bf16_trunc(__expf(t0.z), __expf(t0.w));
      uu[2] = pack_bf16_trunc(__expf(t1.x), __expf(t1.y));
      uu[3] = pack_bf16_trunc(__expf(t1.z), __expf(t1.w));
      __builtin_memcpy(&Ef[mr][kt], uu, 16);
    }

  f32x16 zero16;
#pragma unroll
  for (int i = 0; i < 16; ++i) zero16[i] = 0.0f;

  const size_t FSTRIDE = (size_t)BATCH * TAG;
  const float* fptr = feats + (size_t)(c * L) * FSTRIDE + (size_t)b * TAG + lane;
  const float* mptr = mask + (size_t)(c * L) * BATCH + b;

  float fbuf[PD], mbuf[PD];
#pragma unroll
  for (int d = 0; d < PD; ++d) {
    fbuf[d] = fptr[(size_t)d * FSTRIDE];
    mbuf[d] = mptr[(size_t)d * BATCH];
  }

  float acc_log = 0.0f;
  float inv_c = 1.0f;  // pending renorm scale, applied at next group's d==0
  int fin_p = 0;       // LDS buffer parity holding final M

  for (int sb = 0; sb < L; sb += PD) {
#pragma unroll
    for (int d = 0; d < PD; ++d) {
      const float fcur = fbuf[d];
      const float mcur = mbuf[d];
      // lane-uniform monotone mask: scalar test
      if (__builtin_amdgcn_readfirstlane(__float_as_uint(mcur)) == 0u) {
        fin_p = d & 1;
        goto fin;
      }
      int sp = sb + d + PD;
      sp = (sp < L) ? sp : (L - 1);
      fbuf[d] = fptr[(size_t)sp * FSTRIDE];
      mbuf[d] = mptr[(size_t)sp * BATCH];

      // row scales; fold pending renorm at group start (off critical path)
      if (d == 0) {
        f_lds[lane] = __expf(fcur) * inv_c;
        inv_c = 1.0f;
      } else {
        f_lds[lane] = __expf(fcur);
      }

      const char* rbuf = (const char*)&Mlds[d & 1][0];
      char* wbuf = (char*)&Mlds[(d & 1) ^ 1][0];

      // B-frags [kt][nc]: lane-contiguous b128
      short8 Bf[4][2];
#pragma unroll
      for (int kt = 0; kt < 4; ++kt)
#pragma unroll
        for (int nc = 0; nc < 2; ++nc)
          __builtin_memcpy(&Bf[kt][nc], rbuf + (kt * 2 + nc) * 1024 + lane * 16, 16);

      // G = E*M : 2x2 tiles of 32x32, K=64 via 4 chained 32x32x16 (4-apart dependent)
      f32x16 acc[2][2];
#pragma unroll
      for (int mr = 0; mr < 2; ++mr)
#pragma unroll
        for (int nc = 0; nc < 2; ++nc)
          acc[mr][nc] = __builtin_amdgcn_mfma_f32_32x32x16_bf16(Ef[mr][0], Bf[0][nc], zero16, 0, 0, 0);
#pragma unroll
      for (int kt = 1; kt < 4; ++kt)
#pragma unroll
        for (int mr = 0; mr < 2; ++mr)
#pragma unroll
          for (int nc = 0; nc < 2; ++nc)
            acc[mr][nc] = __builtin_amdgcn_mfma_f32_32x32x16_bf16(Ef[mr][kt], Bf[kt][nc], acc[mr][nc], 0, 0, 0);

      // row scales: C/D row = 32mr + (reg&3) + 8*(reg>>2) + 4h  (broadcast reads)
      f32x4 fr[2][4];
#pragma unroll
      for (int mr = 0; mr < 2; ++mr)
#pragma unroll
        for (int gr = 0; gr < 4; ++gr)
          __builtin_memcpy(&fr[mr][gr], f_lds + 32 * mr + 8 * gr + 4 * h, 16);
#pragma unroll
      for (int mr = 0; mr < 2; ++mr)
#pragma unroll
        for (int nc = 0; nc < 2; ++nc)
#pragma unroll
          for (int gr = 0; gr < 4; ++gr)
#pragma unroll
            for (int i = 0; i < 4; ++i) acc[mr][nc][4 * gr + i] *= fr[mr][gr][i];

      // pack + write to the other buffer
#pragma unroll
      for (int mr = 0; mr < 2; ++mr)
#pragma unroll
        for (int nc = 0; nc < 2; ++nc)
#pragma unroll
          for (int gr = 0; gr < 4; ++gr) {
            uint32 uu[2];
            uu[0] = pack_bf16_trunc(acc[mr][nc][4 * gr], acc[mr][nc][4 * gr + 1]);
            uu[1] = pack_bf16_trunc(acc[mr][nc][4 * gr + 2], acc[mr][nc][4 * gr + 3]);
            __builtin_memcpy(wbuf + ((2 * mr + (gr >> 1)) * 2 + nc) * 1024 +
                                 (c31 + 32 * (gr & 1)) * 16 + 8 * h,
                             uu, 8);
          }

      if (d == PD - 1) {  // renorm bookkeeping; inv applied at NEXT group's d==0
        f32x16 sv = (acc[0][0] + acc[0][1]) + (acc[1][0] + acc[1][1]);
        f32x4 s4 = {sv[0] + sv[4], sv[1] + sv[5], sv[2] + sv[6], sv[3] + sv[7]};
        s4.x += sv[8] + sv[12]; s4.y += sv[9] + sv[13];
        s4.z += sv[10] + sv[14]; s4.w += sv[11] + sv[15];
        float r = (s4.x + s4.y) + (s4.z + s4.w);
#pragma unroll
        for (int off = 32; off >= 1; off >>= 1) r += __shfl_xor(r, off, 64);
        acc_log += __logf(r);
        inv_c = 1.0f / r;
      }
    }
  }
fin:
  // pending-renorm correction: if inv_c != 1, its log was added but never applied to M
  acc_log += __logf(inv_c);
  __builtin_amdgcn_wave_barrier();
  // ---- dump column-major: lane = column n; 8 b128 LDS reads, coalesced 1KB stores ----
  {
    const char* fbuf_lds = (const char*)&Mlds[fin_p][0];
    uint32* dst = wsM + (size_t)bc * 2048;
#pragma unroll
    for (int t = 0; t < 8; ++t) {  // k octet t: rows 8t..8t+7 of column `lane`
      u32x4 v;
      __builtin_memcpy(&v, fbuf_lds + ((t >> 1) * 2 + h) * 1024 + (c31 + 32 * (t & 1)) * 16, 16);
      __builtin_memcpy(dst + t * 256 + lane * 4, &v, 16);
    }
    if (lane == 0) wsL[bc] = acc_log;
  }
}

// ---------------- kernel 2: backward stitch  v^T <- v^T * M_c  (lane = column) ----------------
__global__ __launch_bounds__(64) void crf_stitch_kernel(
    const uint32* __restrict__ wsM, const float* __restrict__ wsL,
    const float* __restrict__ trans, float* __restrict__ out, int K) {
  const int b = blockIdx.x;
  const int lane = threadIdx.x;
  __shared__ __align__(16) float a_lds[TAG];

  u32x4 cur[8], nxt[8];
  {
    const uint32* p0 = wsM + ((size_t)b * K + (K - 1)) * 2048;
#pragma unroll
    for (int t = 0; t < 8; ++t) __builtin_memcpy(&cur[t], p0 + t * 256 + lane * 4, 16);
  }

  float a = __expf(trans[END_IDX * TAG + lane]);  // v0 = exp(trans[END,:])
  float tot = 0.0f;

  for (int c = K - 1; c >= 0; --c) {
    if (c > 0) {
      const uint32* pn = wsM + ((size_t)b * K + (c - 1)) * 2048;
#pragma unroll
      for (int t = 0; t < 8; ++t) __builtin_memcpy(&nxt[t], pn + t * 256 + lane * 4, 16);
    }
    a_lds[lane] = a;
    __builtin_amdgcn_wave_barrier();
    v2f acc[4] = {{0.f, 0.f}, {0.f, 0.f}, {0.f, 0.f}, {0.f, 0.f}};
#pragma unroll
    for (int t = 0; t < 8; ++t) {
#pragma unroll
      for (int e = 0; e < 4; ++e) {
        const uint32 u = cur[t][e];
        v2f m = {__uint_as_float(u << 16), __uint_as_float(u & 0xFFFF0000u)};
        v2f av;
        __builtin_memcpy(&av, a_lds + 8 * t + 2 * e, 8);  // broadcast read
        acc[e] += m * av;                                  // v_pk_fma_f32
      }
    }
    const v2f accT = (acc[0] + acc[1]) + (acc[2] + acc[3]);
    const float s = accT.x + accT.y;
    __builtin_amdgcn_wave_barrier();
    float r = s;
#pragma unroll
    for (int off = 32; off >= 1; off >>= 1) r += __shfl_xor(r, off, 64);
    tot += __logf(r);
    a = s / r;
    if (c > 0) {
#pragma unroll
      for (int t = 0; t < 8; ++t) cur[t] = nxt[t];
    }
  }

  float logs = tot;
  for (int c = 0; c < K; ++c) logs += wsL[b * K + c];
  if (lane == START_IDX) out[b] = logs + __logf(a);
}

// ---------------- fallback (round-1 sequential kernel) if ws too small ----------------
__global__ __launch_bounds__(64) void crf_fwd_fallback(
    const float* __restrict__ feats, const float* __restrict__ mask,
    const float* __restrict__ trans, float* __restrict__ out) {
  const int b = blockIdx.x;
  const int lane = threadIdx.x;
  __shared__ float p_lds[TAG];
  v2f E[TAG / 2];
  {
    const float* row = trans + lane * TAG;
#pragma unroll
    for (int k = 0; k < TAG / 4; ++k) {
      f32x4 tv;
      __builtin_memcpy(&tv, row + 4 * k, 16);
      E[2 * k] = (v2f){__expf(tv.x), __expf(tv.y)};
      E[2 * k + 1] = (v2f){__expf(tv.z), __expf(tv.w)};
    }
  }
  float alpha = (lane == START_IDX) ? 0.0f : -10000.0f;
  float hatM = 0.0f;
  const float* fptr = feats + (size_t)b * TAG + lane;
  const float* mptr = mask + b;
  float fbuf[8], mbuf[8];
#pragma unroll
  for (int d = 0; d < 8; ++d) {
    fbuf[d] = fptr[(size_t)d * (BATCH * TAG)];
    mbuf[d] = mptr[(size_t)d * BATCH];
  }
  for (int sb = 0; sb < S_LEN; sb += 8) {
#pragma unroll
    for (int d = 0; d < 8; ++d) {
      const float fcur = fbuf[d], mcur = mbuf[d];
      if (mcur == 0.0f) goto fin;
      int sp = sb + d + 8;
      sp = (sp < S_LEN) ? sp : (S_LEN - 1);
      fbuf[d] = fptr[(size_t)sp * (BATCH * TAG)];
      mbuf[d] = mptr[(size_t)sp * BATCH];
      const float p = __expf(alpha - hatM);
      p_lds[lane] = p;
      __builtin_amdgcn_wave_barrier();
      v2f a0 = {0.f, 0.f}, a1 = {0.f, 0.f}, a2 = {0.f, 0.f}, a3 = {0.f, 0.f};
#pragma unroll
      for (int k = 0; k < TAG / 8; ++k) {
        v2f p0, p1, p2, p3;
        __builtin_memcpy(&p0, p_lds + 8 * k + 0, 8);
        __builtin_memcpy(&p1, p_lds + 8 * k + 2, 8);
        __builtin_memcpy(&p2, p_lds + 8 * k + 4, 8);
        __builtin_memcpy(&p3, p_lds + 8 * k + 6, 8);
        a0 += p0 * E[4 * k + 0];
        a1 += p1 * E[4 * k + 1];
        a2 += p2 * E[4 * k + 2];
        a3 += p3 * E[4 * k + 3];
      }
      const v2f aT = (a0 + a1) + (a2 + a3);
      alpha = fcur + hatM + __logf(aT.x + aT.y);
      hatM = __uint_as_float(__builtin_amdgcn_readlane(__float_as_uint(alpha), 2));
      __builtin_amdgcn_wave_barrier();
    }
  }
fin : {
  const float aend = alpha + trans[END_IDX * TAG + lane];
  float mx = aend;
#pragma unroll
  for (int off = 32; off >= 1; off >>= 1) mx = fmaxf(mx, __shfl_xor(mx, off, 64));
  float e = __expf(aend - mx);
#pragma unroll
  for (int off = 32; off >= 1; off >>= 1) e += __shfl_xor(e, off, 64);
  if (lane == 0) out[b] = mx + __logf(e);
}
}

extern "C" void kernel_launch(void* const* d_in, const int* in_sizes, int n_in,
                              void* d_out, int out_size, void* d_ws, size_t ws_size,
                              hipStream_t stream) {
  const float* feats = (const float*)d_in[0];
  const float* mask = (const float*)d_in[1];
  const float* trans = (const float*)d_in[2];
  float* out = (float*)d_out;

  int K = 0, kshift = 0;
  {
    int ks = 3;
    for (int k = 8; k >= 2; k >>= 1, --ks) {
      size_t need = (size_t)BATCH * k * (TAG * TAG * 2 + 4) + 256;
      if (ws_size >= need) {
        K = k;
        kshift = ks;
        break;
      }
    }
  }
  if (K == 0) {
    crf_fwd_fallback<<<dim3(BATCH), dim3(64), 0, stream>>>(feats, mask, trans, out);
    return;
  }
  uint32* wsM = (uint32*)d_ws;
  float* wsL = (float*)((char*)d_ws + (size_t)BATCH * K * TAG * TAG * 2);
  crf_chunk_kernel<<<dim3(BATCH * K), dim3(64), 0, stream>>>(feats, mask, trans, wsM, wsL, K,
                                                             S_LEN / K, kshift);
  crf_stitch_kernel<<<dim3(BATCH), dim3(64), 0, stream>>>(wsM, wsL, trans, out, K);
}